// Round 1
// baseline (318.047 us; speedup 1.0000x reference)
//
#include <hip/hip_runtime.h>
#include <hip/hip_bf16.h>
#include <stdint.h>

#define T_SZ 2048
#define B_SZ 64
#define H_SZ 256
#define I_SZ 256
#define M_SZ (B_SZ * T_SZ)          // 131072
#define TBH  (T_SZ * B_SZ * H_SZ)   // 33554432

typedef float f32x4 __attribute__((ext_vector_type(4)));
typedef short s16x8 __attribute__((ext_vector_type(8)));

// RTNE fp32 -> bf16 pair packed into one u32 (low = a, high = b)
__device__ __forceinline__ unsigned pack_bf16(float a, float b) {
    unsigned ua = __float_as_uint(a);
    unsigned ub = __float_as_uint(b);
    ua += 0x7fffu + ((ua >> 16) & 1u);
    ub += 0x7fffu + ((ub >> 16) & 1u);
    return (ua >> 16) | (ub & 0xffff0000u);
}

// ---------------------------------------------------------------------------
// prep: gb[b,h] = sum_j h0[b,j]*W_fh[h,j] + b_fi[h] + b_fh[h]
//       + convert W_fi (fp32 HxI) -> bf16 into Wb
// grid 64 blocks x 256 threads
// ---------------------------------------------------------------------------
__global__ void prep_kernel(const float* __restrict__ h0,
                            const float* __restrict__ W_fi,
                            const float* __restrict__ b_fi,
                            const float* __restrict__ W_fh,
                            const float* __restrict__ b_fh,
                            unsigned short* __restrict__ Wb,
                            float* __restrict__ gb) {
    __shared__ float h0s[H_SZ];
    const int b = blockIdx.x;
    const int h = threadIdx.x;
    h0s[h] = h0[b * H_SZ + h];
    __syncthreads();
    const float4* w4 = (const float4*)(W_fh + (size_t)h * H_SZ);
    float acc = 0.f;
#pragma unroll 8
    for (int j = 0; j < H_SZ / 4; ++j) {
        float4 w = w4[j];
        acc = fmaf(w.x, h0s[4 * j + 0], acc);
        acc = fmaf(w.y, h0s[4 * j + 1], acc);
        acc = fmaf(w.z, h0s[4 * j + 2], acc);
        acc = fmaf(w.w, h0s[4 * j + 3], acc);
    }
    gb[b * H_SZ + h] = acc + b_fi[h] + b_fh[h];

    // convert 4 W_fi elements per thread: 64*256*4 = 65536 total
    const int e = (b * 256 + h) * 4;
    float4 wv = *(const float4*)(W_fi + e);
    uint2 pk;
    pk.x = pack_bf16(wv.x, wv.y);
    pk.y = pack_bf16(wv.z, wv.w);
    *(uint2*)(Wb + e) = pk;
}

// ---------------------------------------------------------------------------
// main: gx = x @ W_fi^T as bf16 MFMA GEMM (M=131072, N=256, K=256),
// BARRIER-FREE / LDS-FREE: MFMA fragments loaded straight from global.
//   A frag (16x16x32 bf16): lane holds x[row + (lane&15)][ (lane>>4)*8 ..+8 ]
//     -> two dwordx4 loads per (mi,kt), converted in-register via cvt_pk.
//   B frag: 16B bf16 load from Wb (L2-hot 128KB), same layout.
// 1-iteration A prefetch; K-offset folds into load immediates (full unroll).
// 128x128 block tile, 4 waves of 64x64, fused LSTM epilogue.
// ---------------------------------------------------------------------------
__global__ __launch_bounds__(256, 3) void lstm_main(
    const float* __restrict__ x,
    const unsigned short* __restrict__ Wb,
    const float* __restrict__ gb,
    const float* __restrict__ c0,
    float* __restrict__ out) {
    const int tid  = threadIdx.x;
    const int lane = tid & 63;
    const int wid  = tid >> 6;

    // XCD-pair swizzle: nt-halves of the same mt land on the same XCD
    // (round-robin model: xcd = bid & 7; pair ids differ by 8 -> same xcd)
    const int orig = blockIdx.x;
    const int mt = (orig >> 4) * 8 + (orig & 7);
    const int nt = (orig >> 3) & 1;
    const int m0 = mt * 128, n0 = nt * 128;
    const int wm = (wid & 1) * 64, wn = (wid >> 1) * 64;
    const int fr = lane & 15;  // fragment row/col within 16
    const int fq = lane >> 4;  // k-chunk quad

    // per-lane fragment base pointers
    const float* abase = x + (size_t)(m0 + wm + fr) * I_SZ + fq * 8;
    const unsigned short* bbase = Wb + (size_t)(n0 + wn + fr) * I_SZ + fq * 8;

    f32x4 acc[4][4];
#pragma unroll
    for (int mi = 0; mi < 4; ++mi)
#pragma unroll
        for (int ni = 0; ni < 4; ++ni)
            acc[mi][ni] = (f32x4){0.f, 0.f, 0.f, 0.f};

    // prefetch A for kt=0 (raw fp32, 32 VGPRs)
    float4 alo[4], ahi[4];
#pragma unroll
    for (int mi = 0; mi < 4; ++mi) {
        const float4* p = (const float4*)(abase + mi * 16 * I_SZ);
        alo[mi] = p[0];
        ahi[mi] = p[1];
    }

#pragma unroll
    for (int kt = 0; kt < 8; ++kt) {
        // B fragments for current kt (L1/L2-hot; latency hidden under cvt)
        s16x8 bf[4];
#pragma unroll
        for (int ni = 0; ni < 4; ++ni)
            bf[ni] = *(const s16x8*)(bbase + ni * 16 * I_SZ + kt * 32);

        // convert prefetched A -> bf16 fragments (v_cvt_pk_bf16_f32)
        s16x8 af[4];
#pragma unroll
        for (int mi = 0; mi < 4; ++mi) {
            union { s16x8 v; __hip_bfloat162 h[4]; } u;
            u.h[0] = __float22bfloat162_rn(make_float2(alo[mi].x, alo[mi].y));
            u.h[1] = __float22bfloat162_rn(make_float2(alo[mi].z, alo[mi].w));
            u.h[2] = __float22bfloat162_rn(make_float2(ahi[mi].x, ahi[mi].y));
            u.h[3] = __float22bfloat162_rn(make_float2(ahi[mi].z, ahi[mi].w));
            af[mi] = u.v;
        }

        // prefetch A for kt+1 (stays in flight across the MFMA cluster)
        if (kt < 7) {
            const int kof = (kt + 1) * 32;
#pragma unroll
            for (int mi = 0; mi < 4; ++mi) {
                const float4* p = (const float4*)(abase + mi * 16 * I_SZ + kof);
                alo[mi] = p[0];
                ahi[mi] = p[1];
            }
        }

#pragma unroll
        for (int mi = 0; mi < 4; ++mi)
#pragma unroll
            for (int ni = 0; ni < 4; ++ni)
                acc[mi][ni] = __builtin_amdgcn_mfma_f32_16x16x32_bf16(
                    af[mi], bf[ni], acc[mi][ni], 0, 0, 0);
    }

    // Epilogue: C/D layout col = lane&15, row = (lane>>4)*4 + reg
    // A wave's 64 M-rows sit inside one batch b (2048 % 64 == 0).
    const int coln = n0 + wn + fr;
    const int bb = (m0 + wm) >> 11;
    float gbv[4], c0v[4];
#pragma unroll
    for (int ni = 0; ni < 4; ++ni) {
        gbv[ni] = gb[bb * H_SZ + coln + ni * 16];
        c0v[ni] = c0[bb * H_SZ + coln + ni * 16];
    }
#pragma unroll
    for (int mi = 0; mi < 4; ++mi) {
#pragma unroll
        for (int r = 0; r < 4; ++r) {
            const int Mg = m0 + wm + mi * 16 + fq * 4 + r;
            const int tt = Mg & (T_SZ - 1);    // % T
            const int obase = tt * (B_SZ * H_SZ) + bb * H_SZ;
            const bool last = (tt == T_SZ - 1);
#pragma unroll
            for (int ni = 0; ni < 4; ++ni) {
                const int h = coln + ni * 16;
                float g = acc[mi][ni][r] + gbv[ni];
                float gc = fminf(15.f, fmaxf(-15.f, g));
                float e = __expf(-gc);
                float s = __builtin_amdgcn_rcpf(1.f + e);        // sigmoid(g)
                float e2 = e * e;
                float m = (1.f - e2) * __builtin_amdgcn_rcpf(1.f + e2);  // tanh(g)
                float cv = s * (c0v[ni] + m);
                float cc = fminf(15.f, fmaxf(-15.f, cv));
                float ec = __expf(-2.f * cc);
                float th = (1.f - ec) * __builtin_amdgcn_rcpf(1.f + ec); // tanh(c)
                float hv = s * th;
                out[obase + h] = hv;
                if (last) {
                    out[TBH + bb * H_SZ + h] = hv;                 // h_last
                    out[TBH + B_SZ * H_SZ + bb * H_SZ + h] = cv;   // c_last
                }
            }
        }
    }
}

extern "C" void kernel_launch(void* const* d_in, const int* in_sizes, int n_in,
                              void* d_out, int out_size, void* d_ws, size_t ws_size,
                              hipStream_t stream) {
    const float* x    = (const float*)d_in[0];
    const float* h0   = (const float*)d_in[1];
    const float* c0   = (const float*)d_in[2];
    const float* W_fi = (const float*)d_in[3];
    const float* b_fi = (const float*)d_in[4];
    const float* W_fh = (const float*)d_in[5];
    const float* b_fh = (const float*)d_in[6];
    float* out = (float*)d_out;

    unsigned short* Wb = (unsigned short*)d_ws;               // 65536 bf16 = 128 KB
    float* gb = (float*)((char*)d_ws + 131072);               // 16384 fp32 = 64 KB

    hipLaunchKernelGGL(prep_kernel, dim3(B_SZ), dim3(H_SZ), 0, stream,
                       h0, W_fi, b_fi, W_fh, b_fh, Wb, gb);
    hipLaunchKernelGGL(lstm_main, dim3(M_SZ / 128 * 2), dim3(256), 0, stream,
                       x, Wb, gb, c0, out);
}